// Round 1
// baseline (190.688 us; speedup 1.0000x reference)
//
#include <hip/hip_runtime.h>

typedef short bf16x8 __attribute__((ext_vector_type(8)));
typedef float f32x4 __attribute__((ext_vector_type(4)));

// B=64, T=2000, E=512, D=1024, CC=32, K=31, H=128, PAD=15

__device__ __forceinline__ unsigned short f2bf(float f) {
  unsigned int u = __builtin_bit_cast(unsigned int, f);
  u += 0x7fffu + ((u >> 16) & 1u);   // RNE
  return (unsigned short)(u >> 16);
}

// ---------------- prep: decb[b][h] = dec_state[b]·W_dec[:,h] + b_enc[h] ----------------
__global__ __launch_bounds__(128) void prep_dec_kernel(
    const float* __restrict__ dec_state, const float* __restrict__ W_dec,
    const float* __restrict__ b_enc, float* __restrict__ decb)
{
  const int b = blockIdx.x;
  const int h = threadIdx.x;
  __shared__ float sd[1024];
  for (int i = h; i < 1024; i += 128) sd[i] = dec_state[b*1024 + i];
  __syncthreads();
  float acc = b_enc[h];
  #pragma unroll 8
  for (int d = 0; d < 1024; ++d) acc = fmaf(sd[d], W_dec[d*128 + h], acc);
  decb[b*128 + h] = acc;
}

// ---------------- prep: M[k][h] = sum_c conv_w[c][k]·W_att[c][h];  WT = bf16(W_encᵀ) chunked ----------------
// WT layout: [kc(8)][h(128)][e&63] bf16  (contiguous 16 KB per 64-e chunk)
__global__ __launch_bounds__(256) void prep_misc_kernel(
    const float* __restrict__ conv_w, const float* __restrict__ W_att,
    const float* __restrict__ W_enc, float* __restrict__ Mkh,
    unsigned short* __restrict__ WT)
{
  if (blockIdx.x == 64) {
    const int h = threadIdx.x;
    if (h < 128) {
      for (int k = 0; k < 31; ++k) {
        float a = 0.f;
        #pragma unroll
        for (int c = 0; c < 32; ++c) a = fmaf(conv_w[c*31 + k], W_att[c*128 + h], a);
        Mkh[k*128 + h] = a;
      }
    }
  } else {
    const int e0 = blockIdx.x * 8;
    #pragma unroll
    for (int j = 0; j < 4; ++j) {
      int idx = threadIdx.x + j*256;
      int el = idx >> 7, h = idx & 127;
      int e = e0 + el;
      float v = W_enc[e*128 + h];
      WT[(e >> 6)*8192 + h*64 + (e & 63)] = f2bf(v);
    }
  }
}

// ---------------- energy[b][t] = tanh(pm + conv + dec)·W_out  (b_out dropped: softmax-invariant) ----------------
__global__ __launch_bounds__(256) void energy_kernel(
    const float* __restrict__ enc, const float* __restrict__ prev,
    const unsigned short* __restrict__ WT, const float* __restrict__ Mkh,
    const float* __restrict__ decb, const float* __restrict__ W_out,
    float* __restrict__ energy)
{
  __shared__ __align__(16) unsigned short sA[64*64];    // enc tile bf16 [t][e], XOR-swizzled
  __shared__ __align__(16) unsigned short sB[128*64];   // W_encᵀ chunk bf16 [h][e], XOR-swizzled
  __shared__ float sM[31*128];
  __shared__ float sDecb[128];
  __shared__ float sWout[128];
  __shared__ float sPrev[96];

  const int b  = blockIdx.y;
  const int t0 = blockIdx.x * 64;
  const int tid = threadIdx.x;

  for (int i = tid; i < 31*128; i += 256) sM[i] = Mkh[i];
  if (tid < 128) { sDecb[tid] = decb[b*128 + tid]; sWout[tid] = W_out[tid]; }
  if (tid < 96) {
    int tt = t0 + tid - 15;
    sPrev[tid] = (tt >= 0 && tt < 2000) ? prev[b*2000 + tt] : 0.f;
  }

  f32x4 acc[8];
  #pragma unroll
  for (int i = 0; i < 8; ++i) acc[i] = (f32x4){0.f, 0.f, 0.f, 0.f};

  const int wave = tid >> 6, lane = tid & 63;
  const int lr = lane & 15, lg = lane >> 4;
  char* sAc = (char*)sA;
  char* sBc = (char*)sB;
  const int xorv = (lr & 7) << 4;
  const int rowA = (wave*16 + lr) * 128;

  // precomputed staging addresses
  const float* encB = enc + (size_t)b * (2000u*512u);
  const float* gsrc[4]; int dstA[4];
  #pragma unroll
  for (int i = 0; i < 4; ++i) {
    int s = tid + i*256;
    int tl = s >> 4, e4 = s & 15;
    int tg = t0 + tl; if (tg > 1999) tg = 1999;   // clamp (last tile); invalid t never written
    gsrc[i] = encB + (size_t)tg*512 + e4*4;
    dstA[i] = (tl*128 + e4*8) ^ ((tl & 7) << 4);
  }
  const int hB = tid >> 1, halfB = tid & 1;

  for (int kc = 0; kc < 8; ++kc) {
    // stage A: 64t x 64e fp32 -> bf16, swizzled
    #pragma unroll
    for (int i = 0; i < 4; ++i) {
      const float4 v = *reinterpret_cast<const float4*>(gsrc[i] + kc*64);
      uint2 w;
      w.x = ((unsigned)f2bf(v.y) << 16) | f2bf(v.x);
      w.y = ((unsigned)f2bf(v.w) << 16) | f2bf(v.z);
      *reinterpret_cast<uint2*>(sAc + dstA[i]) = w;
    }
    // stage B: contiguous 16 KB bf16 chunk
    {
      const unsigned short* src = WT + kc*8192 + tid*32;
      #pragma unroll
      for (int q = 0; q < 4; ++q) {
        uint4 v = *reinterpret_cast<const uint4*>(src + q*8);
        *reinterpret_cast<uint4*>(sBc + ((hB*128 + halfB*64 + q*16) ^ ((hB & 7) << 4))) = v;
      }
    }
    __syncthreads();
    #pragma unroll
    for (int ks = 0; ks < 2; ++ks) {
      bf16x8 a = *reinterpret_cast<const bf16x8*>(sAc + ((rowA + ks*64 + lg*16) ^ xorv));
      #pragma unroll
      for (int nt = 0; nt < 8; ++nt) {
        bf16x8 bb = *reinterpret_cast<const bf16x8*>(
            sBc + (((nt*16 + lr)*128 + ks*64 + lg*16) ^ xorv));
        acc[nt] = __builtin_amdgcn_mfma_f32_16x16x32_bf16(a, bb, acc[nt], 0, 0, 0);
      }
    }
    __syncthreads();
  }

  // conv part: acc[nt][r] += sum_k prev[t0+t+k-15] * M[k][h]
  const int tbase = wave*16 + lg*4;
  #pragma unroll 1
  for (int k = 0; k < 31; ++k) {
    float p0 = sPrev[tbase + 0 + k];
    float p1 = sPrev[tbase + 1 + k];
    float p2 = sPrev[tbase + 2 + k];
    float p3 = sPrev[tbase + 3 + k];
    const float* mrow = sM + k*128 + lr;
    #pragma unroll
    for (int nt = 0; nt < 8; ++nt) {
      float m = mrow[nt*16];
      acc[nt][0] = fmaf(p0, m, acc[nt][0]);
      acc[nt][1] = fmaf(p1, m, acc[nt][1]);
      acc[nt][2] = fmaf(p2, m, acc[nt][2]);
      acc[nt][3] = fmaf(p3, m, acc[nt][3]);
    }
  }

  // + dec, tanh, dot W_out, reduce over h
  float es0 = 0.f, es1 = 0.f, es2 = 0.f, es3 = 0.f;
  #pragma unroll
  for (int nt = 0; nt < 8; ++nt) {
    float dh = sDecb[nt*16 + lr];
    float wo = sWout[nt*16 + lr];
    es0 += tanhf(acc[nt][0] + dh) * wo;
    es1 += tanhf(acc[nt][1] + dh) * wo;
    es2 += tanhf(acc[nt][2] + dh) * wo;
    es3 += tanhf(acc[nt][3] + dh) * wo;
  }
  #pragma unroll
  for (int off = 1; off < 16; off <<= 1) {
    es0 += __shfl_xor(es0, off, 64);
    es1 += __shfl_xor(es1, off, 64);
    es2 += __shfl_xor(es2, off, 64);
    es3 += __shfl_xor(es3, off, 64);
  }
  if (lr == 0) {
    int t = t0 + tbase;
    float ev[4] = {es0, es1, es2, es3};
    #pragma unroll
    for (int r = 0; r < 4; ++r)
      if (t + r < 2000) energy[b*2000 + t + r] = ev[r];
  }
}

// ---------------- softmax over T per b -> att_w ----------------
__global__ __launch_bounds__(256) void softmax_kernel(
    const float* __restrict__ energy, float* __restrict__ attw)
{
  const int b = blockIdx.x, tid = threadIdx.x;
  __shared__ float red[4];
  __shared__ float red2[4];
  float m = -1e30f;
  for (int i = tid; i < 2000; i += 256) m = fmaxf(m, energy[b*2000 + i]);
  #pragma unroll
  for (int off = 1; off < 64; off <<= 1) m = fmaxf(m, __shfl_xor(m, off, 64));
  if ((tid & 63) == 0) red[tid >> 6] = m;
  __syncthreads();
  m = fmaxf(fmaxf(red[0], red[1]), fmaxf(red[2], red[3]));

  float s = 0.f;
  for (int i = tid; i < 2000; i += 256) {
    float p = __expf(energy[b*2000 + i] - m);
    attw[b*2000 + i] = p;
    s += p;
  }
  #pragma unroll
  for (int off = 1; off < 64; off <<= 1) s += __shfl_xor(s, off, 64);
  if ((tid & 63) == 0) red2[tid >> 6] = s;
  __syncthreads();
  s = red2[0] + red2[1] + red2[2] + red2[3];
  float inv = 1.f / s;
  for (int i = tid; i < 2000; i += 256) attw[b*2000 + i] *= inv;
}

// ---------------- att_c partials over t-chunks ----------------
__global__ __launch_bounds__(256) void attc_partial_kernel(
    const float* __restrict__ enc, const float* __restrict__ attw,
    float* __restrict__ part)
{
  const int b = blockIdx.y, ch = blockIdx.x, tid = threadIdx.x;
  const int tstart = ch * 125, tend = tstart + 125;
  float a0 = 0.f, a1 = 0.f;
  const float2* e2 = reinterpret_cast<const float2*>(enc + (size_t)b * (2000u*512u));
  for (int t = tstart; t < tend; ++t) {
    float w = attw[b*2000 + t];
    float2 v = e2[t*256 + tid];
    a0 = fmaf(v.x, w, a0);
    a1 = fmaf(v.y, w, a1);
  }
  part[((b*16 + ch)*512) + tid*2 + 0] = a0;
  part[((b*16 + ch)*512) + tid*2 + 1] = a1;
}

__global__ __launch_bounds__(512) void attc_reduce_kernel(
    const float* __restrict__ part, float* __restrict__ out)
{
  const int b = blockIdx.x, e = threadIdx.x;
  float s = 0.f;
  #pragma unroll
  for (int c = 0; c < 16; ++c) s += part[(b*16 + c)*512 + e];
  out[b*512 + e] = s;
}

// ---------------- launch ----------------
extern "C" void kernel_launch(void* const* d_in, const int* in_sizes, int n_in,
                              void* d_out, int out_size, void* d_ws, size_t ws_size,
                              hipStream_t stream) {
  (void)in_sizes; (void)n_in; (void)out_size; (void)ws_size;
  const float* enc       = (const float*)d_in[0];
  // d_in[1] = text_len: unused by the reference computation
  const float* dec_state = (const float*)d_in[2];
  const float* prev      = (const float*)d_in[3];
  const float* W_enc     = (const float*)d_in[4];
  const float* b_enc     = (const float*)d_in[5];
  const float* W_dec     = (const float*)d_in[6];
  const float* W_att     = (const float*)d_in[7];
  const float* conv_w    = (const float*)d_in[8];
  const float* W_out     = (const float*)d_in[9];
  // d_in[10] = b_out: additive constant in energy -> softmax-invariant, dropped

  char* ws = (char*)d_ws;
  float*          energy = (float*)(ws + 0);             // 64*2000*4   = 512000 (pad to 524288)
  float*          decb   = (float*)(ws + 524288);        // 64*128*4    = 32768
  float*          Mkh    = (float*)(ws + 557056);        // 31*128*4    = 15872 (pad to 16384)
  unsigned short* WT     = (unsigned short*)(ws + 573440); // 512*128*2 = 131072
  float*          part   = (float*)(ws + 704512);        // 64*16*512*4 = 2097152

  float* attc = (float*)d_out;             // (64, 512)
  float* attw = (float*)d_out + 64*512;    // (64, 2000)

  prep_dec_kernel <<<64, 128, 0, stream>>>(dec_state, W_dec, b_enc, decb);
  prep_misc_kernel<<<65, 256, 0, stream>>>(conv_w, W_att, W_enc, Mkh, WT);
  energy_kernel   <<<dim3(32, 64), 256, 0, stream>>>(enc, prev, WT, Mkh, decb, W_out, energy);
  softmax_kernel  <<<64, 256, 0, stream>>>(energy, attw);
  attc_partial_kernel<<<dim3(16, 64), 256, 0, stream>>>(enc, attw, part);
  attc_reduce_kernel <<<64, 512, 0, stream>>>(part, attc);
}